// Round 4
// baseline (133.735 us; speedup 1.0000x reference)
//
#include <hip/hip_runtime.h>
#include <hip/hip_bf16.h>

#define N_TOTAL 8192
#define B_HALF  4096
#define D       256
#define BM      128
#define NTILES  (N_TOTAL / BM)               // 64
#define NBLK    (NTILES * (NTILES + 1) / 2)  // 2080

typedef __bf16 bf16x8v __attribute__((ext_vector_type(8)));
typedef float  f32x4v  __attribute__((ext_vector_type(4)));

__device__ __forceinline__ unsigned short f2bf(float x) {
    unsigned int u = __float_as_uint(x);
    return (unsigned short)((u + 0x7FFFu + ((u >> 16) & 1u)) >> 16);
}
__device__ __forceinline__ float bf2f(unsigned short b) {
    return __uint_as_float(((unsigned int)b) << 16);
}

// ---------------------------------------------------------------------------
// prep: f32 -> bf16 (ws), row norms sq[], col sums s[] (f32 HW atomics),
// per-block f64 sum(sq) partials. Last block (ticket) computes bandwidth:
//   sum(L2) = 2n*sum(sq) - 2*||colsum||^2 ; cexp = log2(e)/(16*bw)
// ---------------------------------------------------------------------------
__global__ void prep_kernel(const float* __restrict__ src,
                            const float* __restrict__ tgt,
                            unsigned short* __restrict__ tb,
                            float* __restrict__ sq,
                            float* __restrict__ s,
                            double* __restrict__ sumsq_part,
                            int* __restrict__ counter,
                            float* __restrict__ cexp) {
    __shared__ float colpart[4][256];
    __shared__ double wsum[4];
    __shared__ double red1[256], red2[256];
    __shared__ int lastFlag;
    int tid = threadIdx.x;
    int wv = tid >> 6, ln = tid & 63;
    int row0 = blockIdx.x * 32 + wv * 8;

    float cp0 = 0.f, cp1 = 0.f, cp2 = 0.f, cp3 = 0.f;
    double dsum = 0.0;

    for (int t = 0; t < 8; ++t) {
        int row = row0 + t;
        const float* p = (row < B_HALF) ? (src + (size_t)row * D)
                                        : (tgt + (size_t)(row - B_HALF) * D);
        float4 v = *(const float4*)(p + ln * 4);
        unsigned short b0 = f2bf(v.x), b1 = f2bf(v.y), b2 = f2bf(v.z), b3 = f2bf(v.w);
        float x0 = bf2f(b0), x1 = bf2f(b1), x2 = bf2f(b2), x3 = bf2f(b3);
        ushort4 u; u.x = b0; u.y = b1; u.z = b2; u.w = b3;
        *(ushort4*)(tb + (size_t)row * D + ln * 4) = u;

        cp0 += x0; cp1 += x1; cp2 += x2; cp3 += x3;

        float sqp = x0 * x0 + x1 * x1 + x2 * x2 + x3 * x3;
        #pragma unroll
        for (int off = 32; off; off >>= 1) sqp += __shfl_down(sqp, off, 64);
        if (ln == 0) { sq[row] = sqp; dsum += (double)sqp; }
    }
    colpart[wv][ln * 4 + 0] = cp0;
    colpart[wv][ln * 4 + 1] = cp1;
    colpart[wv][ln * 4 + 2] = cp2;
    colpart[wv][ln * 4 + 3] = cp3;
    if (ln == 0) wsum[wv] = dsum;
    __syncthreads();
    float cs = colpart[0][tid] + colpart[1][tid] + colpart[2][tid] + colpart[3][tid];
    atomicAdd(&s[tid], cs);
    if (tid == 0) {
        sumsq_part[blockIdx.x] = wsum[0] + wsum[1] + wsum[2] + wsum[3];
        __threadfence();
        lastFlag = (atomicAdd(counter, 1) == (int)gridDim.x - 1);
    }
    __syncthreads();
    if (lastFlag) {
        __threadfence();
        float v = s[tid];
        red1[tid] = sumsq_part[tid];             // 256 blocks
        red2[tid] = (double)v * (double)v;
        __syncthreads();
        for (int off = 128; off; off >>= 1) {
            if (tid < off) { red1[tid] += red1[tid + off]; red2[tid] += red2[tid + off]; }
            __syncthreads();
        }
        if (tid == 0) {
            double sl2 = 2.0 * (double)N_TOTAL * red1[0] - 2.0 * red2[0];
            double bw = sl2 / ((double)N_TOTAL * N_TOTAL - (double)N_TOTAL);
            cexp[0] = (float)(1.4426950408889634 / (16.0 * bw));
        }
    }
}

// ---------------------------------------------------------------------------
// mmd: lower-triangular 128x128 Gram tiles, bf16 MFMA, fused exp epilogue.
// NO LDS staging: tb (4 MB) is L2/L3-resident, so each lane loads its MFMA
// fragments directly from global (16 B/lane; one load = 16 rows x 64 B
// contiguous lines) with a 1-deep register double-buffer. Zero barriers in
// the K-loop -> the latency/barrier serialization that bounded r1-r3 is gone.
// ---------------------------------------------------------------------------
__global__ __launch_bounds__(256)
void mmd_kernel(const unsigned short* __restrict__ tb,
                const float* __restrict__ sq,
                const float* __restrict__ cexp_p,
                double* __restrict__ partials,
                int* __restrict__ counter,
                float* __restrict__ out) {
    __shared__ float sqi[BM], sqj[BM];
    __shared__ float redbuf[4];
    __shared__ double dred[256];
    __shared__ int lastFlag;

    // triangle decode: block t -> (r,c), r >= c
    int t = blockIdx.x;
    int r = (int)((sqrtf(8.0f * (float)t + 1.0f) - 1.0f) * 0.5f);
    while ((r + 1) * (r + 2) / 2 <= t) ++r;
    while (r * (r + 1) / 2 > t) --r;
    int c = t - r * (r + 1) / 2;
    int rowBase = r * BM, colBase = c * BM;

    int tid = threadIdx.x;
    int wv = tid >> 6, ln = tid & 63;
    int wr = wv >> 1, wc = wv & 1;
    int lo = ln & 15, hi = ln >> 4;

    if (tid < BM) sqi[tid] = sq[rowBase + tid];
    else          sqj[tid - BM] = sq[colBase + (tid - BM)];
    float cexp = cexp_p[0];
    __syncthreads();                 // the block's only pre-epilogue barrier

    // per-lane fragment base pointers:
    // frag element = tb[(base + frag*16 + lo) * D + kk*32 + hi*8], 8 bf16
    const unsigned short* ga = tb + (size_t)(rowBase + wr * 64 + lo) * D + hi * 8;
    const unsigned short* gb = tb + (size_t)(colBase + wc * 64 + lo) * D + hi * 8;

    f32x4v acc[4][4] = {};
    bf16x8v a[2][4], b[2][4];

    #pragma unroll
    for (int mi = 0; mi < 4; ++mi) a[0][mi] = *(const bf16x8v*)(ga + mi * 16 * D);
    #pragma unroll
    for (int ni = 0; ni < 4; ++ni) b[0][ni] = *(const bf16x8v*)(gb + ni * 16 * D);

    #pragma unroll
    for (int kk = 0; kk < 8; ++kk) {        // K = 8 x 32
        const int cur = kk & 1, nxt = cur ^ 1;
        if (kk < 7) {
            #pragma unroll
            for (int mi = 0; mi < 4; ++mi)
                a[nxt][mi] = *(const bf16x8v*)(ga + mi * 16 * D + (kk + 1) * 32);
            #pragma unroll
            for (int ni = 0; ni < 4; ++ni)
                b[nxt][ni] = *(const bf16x8v*)(gb + ni * 16 * D + (kk + 1) * 32);
        }
        #pragma unroll
        for (int mi = 0; mi < 4; ++mi)
            #pragma unroll
            for (int ni = 0; ni < 4; ++ni)
                acc[mi][ni] = __builtin_amdgcn_mfma_f32_16x16x32_bf16(
                    a[cur][mi], b[cur][ni], acc[mi][ni], 0, 0, 0);
    }

    // epilogue: arg = (2*gram - (sq_i+sq_j)) * cexp ; kernels e0..e0^16
    // C/D layout (16x16x32): col = lane&15, row = (lane>>4)*4 + reg
    float tacc = 0.f;
    #pragma unroll
    for (int mi = 0; mi < 4; ++mi) {
        float si4[4];
        #pragma unroll
        for (int rg = 0; rg < 4; ++rg)
            si4[rg] = sqi[wr * 64 + mi * 16 + hi * 4 + rg];
        #pragma unroll
        for (int ni = 0; ni < 4; ++ni) {
            float sj = sqj[wc * 64 + ni * 16 + lo];
            #pragma unroll
            for (int rg = 0; rg < 4; ++rg) {
                float arg = (2.0f * acc[mi][ni][rg] - (si4[rg] + sj)) * cexp;
                float e0 = __builtin_amdgcn_exp2f(arg);
                float e2 = e0 * e0, e4 = e2 * e2, e8 = e4 * e4, e16 = e8 * e8;
                tacc += (e0 + e2) + ((e4 + e8) + e16);
            }
        }
    }
    // tile-uniform sign (B_HALF is a multiple of BM) + triangle weight
    float w = ((r < B_HALF / BM) == (c < B_HALF / BM)) ? 1.f : -1.f;
    if (r != c) w *= 2.f;
    tacc *= w;

    #pragma unroll
    for (int off = 32; off; off >>= 1) tacc += __shfl_down(tacc, off, 64);
    if (ln == 0) redbuf[wv] = tacc;
    __syncthreads();

    if (tid == 0) {
        partials[blockIdx.x] =
            (double)(redbuf[0] + redbuf[1] + redbuf[2] + redbuf[3]);
        __threadfence();
        lastFlag = (atomicAdd(counter, 1) == (int)gridDim.x - 1);
    }
    __syncthreads();
    if (lastFlag) {
        __threadfence();
        double d = 0.0;
        for (int i = tid; i < NBLK; i += 256) d += partials[i];
        dred[tid] = d;
        __syncthreads();
        for (int off = 128; off; off >>= 1) {
            if (tid < off) dred[tid] += dred[tid + off];
            __syncthreads();
        }
        if (tid == 0)
            out[0] = (float)(dred[0] / (5.0 * (double)B_HALF * (double)B_HALF));
    }
}

// ---------------------------------------------------------------------------
extern "C" void kernel_launch(void* const* d_in, const int* in_sizes, int n_in,
                              void* d_out, int out_size, void* d_ws, size_t ws_size,
                              hipStream_t stream) {
    const float* src = (const float*)d_in[0];
    const float* tgt = (const float*)d_in[1];
    float* out = (float*)d_out;
    char* ws = (char*)d_ws;

    int*    cntPrep  = (int*)(ws + 0);
    int*    cntMmd   = (int*)(ws + 8);
    float*  cexp     = (float*)(ws + 16);
    float*  s        = (float*)(ws + 64);      // 256 f32, atomic-accumulated
    double* ssqpart  = (double*)(ws + 2048);   // 256 f64, fully overwritten
    float*  sq       = (float*)(ws + 4096);    // 8192 f32
    double* partials = (double*)(ws + 40960);  // 2080 f64, fully overwritten
    unsigned short* tb = (unsigned short*)(ws + 65536);  // 4 MB bf16

    // zero counters + s[] (ws poisoned 0xAA; not re-poisoned between replays)
    hipMemsetAsync(ws, 0, 2048, stream);

    prep_kernel<<<N_TOTAL / 32, 256, 0, stream>>>(src, tgt, tb, sq, s,
                                                  ssqpart, cntPrep, cexp);
    mmd_kernel<<<NBLK, 256, 0, stream>>>(tb, sq, cexp, partials, cntMmd, out);
}

// Round 5
// 88.189 us; speedup vs baseline: 1.5165x; 1.5165x over previous
//
#include <hip/hip_runtime.h>
#include <hip/hip_bf16.h>

#define N_TOTAL 8192
#define B_HALF  4096
#define D       256
#define BM      128
#define BK      64
#define NTILES  (N_TOTAL / BM)               // 64
#define NBLK    (NTILES * (NTILES + 1) / 2)  // 2080

typedef __bf16 bf16x8v __attribute__((ext_vector_type(8)));
typedef float  f32x4v  __attribute__((ext_vector_type(4)));

__device__ __forceinline__ unsigned short f2bf(float x) {
    unsigned int u = __float_as_uint(x);
    return (unsigned short)((u + 0x7FFFu + ((u >> 16) & 1u)) >> 16);
}
__device__ __forceinline__ float bf2f(unsigned short b) {
    return __uint_as_float(((unsigned int)b) << 16);
}

__device__ __forceinline__ void gload_lds16(const void* g, void* l) {
    __builtin_amdgcn_global_load_lds(
        (const __attribute__((address_space(1))) unsigned int*)g,
        (__attribute__((address_space(3))) unsigned int*)l,
        16, 0, 0);
}

// ---------------------------------------------------------------------------
// prep: f32 -> bf16 (ws), row norms sq[], col sums s[] (f32 HW atomics),
// per-block f64 sum(sq) partials. Last block (ticket) computes bandwidth:
//   sum(L2) = 2n*sum(sq) - 2*||colsum||^2 ; cexp = log2(e)/(16*bw)
// ---------------------------------------------------------------------------
__global__ void prep_kernel(const float* __restrict__ src,
                            const float* __restrict__ tgt,
                            unsigned short* __restrict__ tb,
                            float* __restrict__ sq,
                            float* __restrict__ s,
                            double* __restrict__ sumsq_part,
                            int* __restrict__ counter,
                            float* __restrict__ cexp) {
    __shared__ float colpart[4][256];
    __shared__ double wsum[4];
    __shared__ double red1[256], red2[256];
    __shared__ int lastFlag;
    int tid = threadIdx.x;
    int wv = tid >> 6, ln = tid & 63;
    int row0 = blockIdx.x * 32 + wv * 8;

    float cp0 = 0.f, cp1 = 0.f, cp2 = 0.f, cp3 = 0.f;
    double dsum = 0.0;

    for (int t = 0; t < 8; ++t) {
        int row = row0 + t;
        const float* p = (row < B_HALF) ? (src + (size_t)row * D)
                                        : (tgt + (size_t)(row - B_HALF) * D);
        float4 v = *(const float4*)(p + ln * 4);
        unsigned short b0 = f2bf(v.x), b1 = f2bf(v.y), b2 = f2bf(v.z), b3 = f2bf(v.w);
        float x0 = bf2f(b0), x1 = bf2f(b1), x2 = bf2f(b2), x3 = bf2f(b3);
        ushort4 u; u.x = b0; u.y = b1; u.z = b2; u.w = b3;
        *(ushort4*)(tb + (size_t)row * D + ln * 4) = u;

        cp0 += x0; cp1 += x1; cp2 += x2; cp3 += x3;

        float sqp = x0 * x0 + x1 * x1 + x2 * x2 + x3 * x3;
        #pragma unroll
        for (int off = 32; off; off >>= 1) sqp += __shfl_down(sqp, off, 64);
        if (ln == 0) { sq[row] = sqp; dsum += (double)sqp; }
    }
    colpart[wv][ln * 4 + 0] = cp0;
    colpart[wv][ln * 4 + 1] = cp1;
    colpart[wv][ln * 4 + 2] = cp2;
    colpart[wv][ln * 4 + 3] = cp3;
    if (ln == 0) wsum[wv] = dsum;
    __syncthreads();
    float cs = colpart[0][tid] + colpart[1][tid] + colpart[2][tid] + colpart[3][tid];
    atomicAdd(&s[tid], cs);
    if (tid == 0) {
        sumsq_part[blockIdx.x] = wsum[0] + wsum[1] + wsum[2] + wsum[3];
        __threadfence();
        lastFlag = (atomicAdd(counter, 1) == (int)gridDim.x - 1);
    }
    __syncthreads();
    if (lastFlag) {
        __threadfence();
        float v = s[tid];
        red1[tid] = sumsq_part[tid];             // 256 blocks
        red2[tid] = (double)v * (double)v;
        __syncthreads();
        for (int off = 128; off; off >>= 1) {
            if (tid < off) { red1[tid] += red1[tid + off]; red2[tid] += red2[tid + off]; }
            __syncthreads();
        }
        if (tid == 0) {
            double sl2 = 2.0 * (double)N_TOTAL * red1[0] - 2.0 * red2[0];
            double bw = sl2 / ((double)N_TOTAL * N_TOTAL - (double)N_TOTAL);
            cexp[0] = (float)(1.4426950408889634 / (16.0 * bw));
        }
    }
}

// ---------------------------------------------------------------------------
// mmd: lower-triangular 128x128 Gram tiles, bf16 MFMA, fused exp epilogue.
// r1's proven m97-style structure (single-buffer LDS, stage -> syncthreads ->
// ds_read -> MFMA -> syncthreads, 4 blocks/CU implicit cross-block overlap)
// + the XOR swizzle (both-sides: pre-swizzled global source because
// global_load_lds writes linearly; same XOR on ds_read) -> 0 bank conflicts.
// Fragments scoped per-kk (32 live VGPRs) to stay off the spill cliff.
// ---------------------------------------------------------------------------
__device__ __forceinline__ void stage_tiles(const unsigned short* __restrict__ tb,
                                            int rowBase, int colBase, int kb0,
                                            int wv, int ln,
                                            unsigned short* ldsA,
                                            unsigned short* ldsB) {
    #pragma unroll
    for (int i = 0; i < 4; ++i) {
        int o = i * 4096 + wv * 1024 + ln * 16;          // linear LDS byte off
        int rowl = o >> 7;                               // 128 B per row
        int colb = (o & 127) ^ ((rowl & 7) << 4);        // pre-swizzled source
        gload_lds16(tb + (size_t)(rowBase + rowl) * D + kb0 + (colb >> 1),
                    (char*)ldsA + i * 4096 + wv * 1024);
        gload_lds16(tb + (size_t)(colBase + rowl) * D + kb0 + (colb >> 1),
                    (char*)ldsB + i * 4096 + wv * 1024);
    }
}

__global__ __launch_bounds__(256)
void mmd_kernel(const unsigned short* __restrict__ tb,
                const float* __restrict__ sq,
                const float* __restrict__ cexp_p,
                double* __restrict__ partials,
                int* __restrict__ counter,
                float* __restrict__ out) {
    __shared__ __align__(16) unsigned short ldsA[BM * BK];  // 16 KB
    __shared__ __align__(16) unsigned short ldsB[BM * BK];  // 16 KB
    __shared__ float sqi[BM], sqj[BM];
    __shared__ float redbuf[4];
    __shared__ double dred[256];
    __shared__ int lastFlag;

    // triangle decode: block t -> (r,c), r >= c
    int t = blockIdx.x;
    int r = (int)((sqrtf(8.0f * (float)t + 1.0f) - 1.0f) * 0.5f);
    while ((r + 1) * (r + 2) / 2 <= t) ++r;
    while (r * (r + 1) / 2 > t) --r;
    int c = t - r * (r + 1) / 2;
    int rowBase = r * BM, colBase = c * BM;

    int tid = threadIdx.x;
    int wv = tid >> 6, ln = tid & 63;
    int wr = wv >> 1, wc = wv & 1;
    int lo = ln & 15, hi = ln >> 4;

    if (tid < BM) sqi[tid] = sq[rowBase + tid];
    else          sqj[tid - BM] = sq[colBase + (tid - BM)];
    float cexp = cexp_p[0];

    f32x4v acc[4][4] = {};

    for (int ks = 0; ks < D / BK; ++ks) {
        stage_tiles(tb, rowBase, colBase, ks * BK, wv, ln, ldsA, ldsB);
        __syncthreads();                       // drains vmcnt; tile visible

        #pragma unroll
        for (int kk = 0; kk < 2; ++kk) {
            bf16x8v a[4], b[4];
            #pragma unroll
            for (int mi = 0; mi < 4; ++mi) {
                int rowl = wr * 64 + mi * 16 + lo;
                int colb = (kk * 64 + hi * 16) ^ ((rowl & 7) << 4);
                a[mi] = *(const bf16x8v*)((const char*)ldsA + rowl * 128 + colb);
            }
            #pragma unroll
            for (int ni = 0; ni < 4; ++ni) {
                int rowl = wc * 64 + ni * 16 + lo;
                int colb = (kk * 64 + hi * 16) ^ ((rowl & 7) << 4);
                b[ni] = *(const bf16x8v*)((const char*)ldsB + rowl * 128 + colb);
            }
            #pragma unroll
            for (int mi = 0; mi < 4; ++mi)
                #pragma unroll
                for (int ni = 0; ni < 4; ++ni)
                    acc[mi][ni] = __builtin_amdgcn_mfma_f32_16x16x32_bf16(
                        a[mi], b[ni], acc[mi][ni], 0, 0, 0);
        }
        __syncthreads();                       // all reads done before restage
    }

    // epilogue: arg = (2*gram - (sq_i+sq_j)) * cexp ; kernels e0..e0^16
    // C/D layout (16x16x32): col = lane&15, row = (lane>>4)*4 + reg
    float tacc = 0.f;
    #pragma unroll
    for (int mi = 0; mi < 4; ++mi) {
        float si4[4];
        #pragma unroll
        for (int rg = 0; rg < 4; ++rg)
            si4[rg] = sqi[wr * 64 + mi * 16 + hi * 4 + rg];
        #pragma unroll
        for (int ni = 0; ni < 4; ++ni) {
            float sj = sqj[wc * 64 + ni * 16 + lo];
            #pragma unroll
            for (int rg = 0; rg < 4; ++rg) {
                float arg = (2.0f * acc[mi][ni][rg] - (si4[rg] + sj)) * cexp;
                float e0 = __builtin_amdgcn_exp2f(arg);
                float e2 = e0 * e0, e4 = e2 * e2, e8 = e4 * e4, e16 = e8 * e8;
                tacc += (e0 + e2) + ((e4 + e8) + e16);
            }
        }
    }
    // tile-uniform sign (B_HALF is a multiple of BM) + triangle weight
    float w = ((r < B_HALF / BM) == (c < B_HALF / BM)) ? 1.f : -1.f;
    if (r != c) w *= 2.f;
    tacc *= w;

    #pragma unroll
    for (int off = 32; off; off >>= 1) tacc += __shfl_down(tacc, off, 64);
    if (ln == 0) redbuf[wv] = tacc;
    __syncthreads();

    if (tid == 0) {
        partials[blockIdx.x] =
            (double)(redbuf[0] + redbuf[1] + redbuf[2] + redbuf[3]);
        __threadfence();
        lastFlag = (atomicAdd(counter, 1) == (int)gridDim.x - 1);
    }
    __syncthreads();
    if (lastFlag) {
        __threadfence();
        double d = 0.0;
        for (int i = tid; i < NBLK; i += 256) d += partials[i];
        dred[tid] = d;
        __syncthreads();
        for (int off = 128; off; off >>= 1) {
            if (tid < off) dred[tid] += dred[tid + off];
            __syncthreads();
        }
        if (tid == 0)
            out[0] = (float)(dred[0] / (5.0 * (double)B_HALF * (double)B_HALF));
    }
}

// ---------------------------------------------------------------------------
extern "C" void kernel_launch(void* const* d_in, const int* in_sizes, int n_in,
                              void* d_out, int out_size, void* d_ws, size_t ws_size,
                              hipStream_t stream) {
    const float* src = (const float*)d_in[0];
    const float* tgt = (const float*)d_in[1];
    float* out = (float*)d_out;
    char* ws = (char*)d_ws;

    int*    cntPrep  = (int*)(ws + 0);
    int*    cntMmd   = (int*)(ws + 8);
    float*  cexp     = (float*)(ws + 16);
    float*  s        = (float*)(ws + 64);      // 256 f32, atomic-accumulated
    double* ssqpart  = (double*)(ws + 2048);   // 256 f64, fully overwritten
    float*  sq       = (float*)(ws + 4096);    // 8192 f32
    double* partials = (double*)(ws + 40960);  // 2080 f64, fully overwritten
    unsigned short* tb = (unsigned short*)(ws + 65536);  // 4 MB bf16

    // zero counters + s[] (ws poisoned 0xAA; not re-poisoned between replays)
    hipMemsetAsync(ws, 0, 2048, stream);

    prep_kernel<<<N_TOTAL / 32, 256, 0, stream>>>(src, tgt, tb, sq, s,
                                                  ssqpart, cntPrep, cexp);
    mmd_kernel<<<NBLK, 256, 0, stream>>>(tb, sq, cexp, partials, cntMmd, out);
}

// Round 6
// 63.958 us; speedup vs baseline: 2.0910x; 1.3789x over previous
//
#include <hip/hip_runtime.h>
#include <hip/hip_bf16.h>

#define N_TOTAL 8192
#define B_HALF  4096
#define D       256
#define BM      128
#define BK      64
#define NTILES  (N_TOTAL / BM)               // 64
#define NBLK    (NTILES * (NTILES + 1) / 2)  // 2080
#define NPAIR   (NBLK / 2)                   // 1040

typedef __bf16 bf16x8v __attribute__((ext_vector_type(8)));
typedef float  f32x4v  __attribute__((ext_vector_type(4)));

__device__ __forceinline__ unsigned short f2bf(float x) {
    unsigned int u = __float_as_uint(x);
    return (unsigned short)((u + 0x7FFFu + ((u >> 16) & 1u)) >> 16);
}
__device__ __forceinline__ float bf2f(unsigned short b) {
    return __uint_as_float(((unsigned int)b) << 16);
}

__device__ __forceinline__ void gload_lds16(const void* g, void* l) {
    __builtin_amdgcn_global_load_lds(
        (const __attribute__((address_space(1))) unsigned int*)g,
        (__attribute__((address_space(3))) unsigned int*)l,
        16, 0, 0);
}

// ---------------------------------------------------------------------------
// prep: f32 -> bf16 (ws), row norms sq[], col sums s[] (f32 HW atomics),
// per-block f64 sum(sq) partials. Last block (ticket) computes bandwidth:
//   sum(L2) = 2n*sum(sq) - 2*||colsum||^2 ; cexp = log2(e)/(16*bw)
// ---------------------------------------------------------------------------
__global__ void prep_kernel(const float* __restrict__ src,
                            const float* __restrict__ tgt,
                            unsigned short* __restrict__ tb,
                            float* __restrict__ sq,
                            float* __restrict__ s,
                            double* __restrict__ sumsq_part,
                            int* __restrict__ counter,
                            float* __restrict__ cexp) {
    __shared__ float colpart[4][256];
    __shared__ double wsum[4];
    __shared__ double red1[256], red2[256];
    __shared__ int lastFlag;
    int tid = threadIdx.x;
    int wv = tid >> 6, ln = tid & 63;
    int row0 = blockIdx.x * 32 + wv * 8;

    float cp0 = 0.f, cp1 = 0.f, cp2 = 0.f, cp3 = 0.f;
    double dsum = 0.0;

    for (int t = 0; t < 8; ++t) {
        int row = row0 + t;
        const float* p = (row < B_HALF) ? (src + (size_t)row * D)
                                        : (tgt + (size_t)(row - B_HALF) * D);
        float4 v = *(const float4*)(p + ln * 4);
        unsigned short b0 = f2bf(v.x), b1 = f2bf(v.y), b2 = f2bf(v.z), b3 = f2bf(v.w);
        float x0 = bf2f(b0), x1 = bf2f(b1), x2 = bf2f(b2), x3 = bf2f(b3);
        ushort4 u; u.x = b0; u.y = b1; u.z = b2; u.w = b3;
        *(ushort4*)(tb + (size_t)row * D + ln * 4) = u;

        cp0 += x0; cp1 += x1; cp2 += x2; cp3 += x3;

        float sqp = x0 * x0 + x1 * x1 + x2 * x2 + x3 * x3;
        #pragma unroll
        for (int off = 32; off; off >>= 1) sqp += __shfl_down(sqp, off, 64);
        if (ln == 0) { sq[row] = sqp; dsum += (double)sqp; }
    }
    colpart[wv][ln * 4 + 0] = cp0;
    colpart[wv][ln * 4 + 1] = cp1;
    colpart[wv][ln * 4 + 2] = cp2;
    colpart[wv][ln * 4 + 3] = cp3;
    if (ln == 0) wsum[wv] = dsum;
    __syncthreads();
    float cs = colpart[0][tid] + colpart[1][tid] + colpart[2][tid] + colpart[3][tid];
    atomicAdd(&s[tid], cs);
    if (tid == 0) {
        sumsq_part[blockIdx.x] = wsum[0] + wsum[1] + wsum[2] + wsum[3];
        __threadfence();
        lastFlag = (atomicAdd(counter, 1) == (int)gridDim.x - 1);
    }
    __syncthreads();
    if (lastFlag) {
        __threadfence();
        float v = s[tid];
        red1[tid] = sumsq_part[tid];             // 256 blocks
        red2[tid] = (double)v * (double)v;
        __syncthreads();
        for (int off = 128; off; off >>= 1) {
            if (tid < off) { red1[tid] += red1[tid + off]; red2[tid] += red2[tid + off]; }
            __syncthreads();
        }
        if (tid == 0) {
            double sl2 = 2.0 * (double)N_TOTAL * red1[0] - 2.0 * red2[0];
            double bw = sl2 / ((double)N_TOTAL * N_TOTAL - (double)N_TOTAL);
            cexp[0] = (float)(1.4426950408889634 / (16.0 * bw));
        }
    }
}

// ---------------------------------------------------------------------------
// mmd: each block = TWO consecutive triangle tiles (128x128), 8 fat K-steps,
// T3-minimum schedule: dbuf LDS, stage(s+1) issued FIRST, then ds_read+MFMA
// of step s, then ONE vmcnt(0)+s_barrier per step. Tile0's exp epilogue
// overlaps tile1's first stage. Plain partials store (no fence/atomic ->
// no per-block L2 invalidation; tb stays L2-hot).
// ---------------------------------------------------------------------------
__device__ __forceinline__ void stage_tiles(const unsigned short* __restrict__ tb,
                                            int rowBase, int colBase, int kb0,
                                            int wv, int ln,
                                            unsigned short* ldsA,
                                            unsigned short* ldsB) {
    #pragma unroll
    for (int i = 0; i < 4; ++i) {
        int o = i * 4096 + wv * 1024 + ln * 16;          // linear LDS byte off
        int rowl = o >> 7;                               // 128 B per row
        int colb = (o & 127) ^ ((rowl & 7) << 4);        // pre-swizzled source
        gload_lds16(tb + (size_t)(rowBase + rowl) * D + kb0 + (colb >> 1),
                    (char*)ldsA + i * 4096 + wv * 1024);
        gload_lds16(tb + (size_t)(colBase + rowl) * D + kb0 + (colb >> 1),
                    (char*)ldsB + i * 4096 + wv * 1024);
    }
}

__global__ __launch_bounds__(256, 2)
void mmd_kernel(const unsigned short* __restrict__ tb,
                const float* __restrict__ sq,
                const float* __restrict__ cexp_p,
                double* __restrict__ partials) {
    __shared__ __align__(16) unsigned short lds[2][2][BM * BK];  // 64 KB
    __shared__ float sqi[2][BM], sqj[2][BM];
    __shared__ float redbuf[4];

    // decode pair: tiles t0 = 2*bid, t1 = t0+1 of the lower triangle
    int t0 = blockIdx.x * 2;
    int r0 = (int)((sqrtf(8.0f * (float)t0 + 1.0f) - 1.0f) * 0.5f);
    while ((r0 + 1) * (r0 + 2) / 2 <= t0) ++r0;
    while (r0 * (r0 + 1) / 2 > t0) --r0;
    int c0 = t0 - r0 * (r0 + 1) / 2;
    int r1 = r0, c1 = c0 + 1;
    if (c1 > r0) { r1 = r0 + 1; c1 = 0; }

    const int rowB[2] = {r0 * BM, r1 * BM};
    const int colB[2] = {c0 * BM, c1 * BM};
    // per-tile weight: sign (block-uniform; B_HALF multiple of BM) x triangle
    float wt[2];
    wt[0] = (((r0 < NTILES / 2) == (c0 < NTILES / 2)) ? 1.f : -1.f) * (r0 != c0 ? 2.f : 1.f);
    wt[1] = (((r1 < NTILES / 2) == (c1 < NTILES / 2)) ? 1.f : -1.f) * (r1 != c1 ? 2.f : 1.f);

    int tid = threadIdx.x;
    int wv = tid >> 6, ln = tid & 63;
    int wr = wv >> 1, wc = wv & 1;
    int lo = ln & 15, hi = ln >> 4;

    // stage step 0 (tile0, ks=0) immediately; overlap sq loads under it
    stage_tiles(tb, rowB[0], colB[0], 0, wv, ln, lds[0][0], lds[0][1]);

    if (tid < BM) { sqi[0][tid] = sq[rowB[0] + tid]; sqi[1][tid] = sq[rowB[1] + tid]; }
    else { int u = tid - BM; sqj[0][u] = sq[colB[0] + u]; sqj[1][u] = sq[colB[1] + u]; }
    float cexp = cexp_p[0];

    __syncthreads();                 // drains vmcnt(0)+lgkmcnt(0): buf0 ready

    f32x4v acc[4][4] = {};
    float tacc = 0.f;

    #pragma unroll
    for (int s = 0; s < 8; ++s) {    // step = (tile = s>>2, ks = s&3)
        const int cur = s & 1;
        const int tile = s >> 2;

        if (s < 7) {                 // issue next step's stage FIRST
            const int tn = (s + 1) >> 2, kn = (s + 1) & 3;
            stage_tiles(tb, rowB[tn], colB[tn], kn * BK, wv, ln,
                        lds[cur ^ 1][0], lds[cur ^ 1][1]);
            __builtin_amdgcn_sched_barrier(0);   // keep stage issue first
        }

        // read this step's fragments (swizzled, conflict-free)
        bf16x8v a[2][4], b[2][4];
        #pragma unroll
        for (int kk = 0; kk < 2; ++kk) {
            #pragma unroll
            for (int mi = 0; mi < 4; ++mi) {
                int rowl = wr * 64 + mi * 16 + lo;
                int colb = (kk * 64 + hi * 16) ^ ((rowl & 7) << 4);
                a[kk][mi] = *(const bf16x8v*)((const char*)lds[cur][0] + rowl * 128 + colb);
            }
            #pragma unroll
            for (int ni = 0; ni < 4; ++ni) {
                int rowl = wc * 64 + ni * 16 + lo;
                int colb = (kk * 64 + hi * 16) ^ ((rowl & 7) << 4);
                b[kk][ni] = *(const bf16x8v*)((const char*)lds[cur][1] + rowl * 128 + colb);
            }
        }

        __builtin_amdgcn_s_setprio(1);
        #pragma unroll
        for (int kk = 0; kk < 2; ++kk)
            #pragma unroll
            for (int mi = 0; mi < 4; ++mi)
                #pragma unroll
                for (int ni = 0; ni < 4; ++ni)
                    acc[mi][ni] = __builtin_amdgcn_mfma_f32_16x16x32_bf16(
                        a[kk][mi], b[kk][ni], acc[mi][ni], 0, 0, 0);
        __builtin_amdgcn_s_setprio(0);

        if ((s & 3) == 3) {
            // epilogue for `tile` (VALU; overlaps the in-flight stage)
            // C/D layout (16x16x32): col = lane&15, row = (lane>>4)*4 + reg
            float ep = 0.f;
            #pragma unroll
            for (int mi = 0; mi < 4; ++mi) {
                float si4[4];
                #pragma unroll
                for (int rg = 0; rg < 4; ++rg)
                    si4[rg] = sqi[tile][wr * 64 + mi * 16 + hi * 4 + rg];
                #pragma unroll
                for (int ni = 0; ni < 4; ++ni) {
                    float sj = sqj[tile][wc * 64 + ni * 16 + lo];
                    #pragma unroll
                    for (int rg = 0; rg < 4; ++rg) {
                        float arg = (2.0f * acc[mi][ni][rg] - (si4[rg] + sj)) * cexp;
                        float e0 = __builtin_amdgcn_exp2f(arg);
                        float e2 = e0 * e0, e4 = e2 * e2, e8 = e4 * e4, e16 = e8 * e8;
                        ep += (e0 + e2) + ((e4 + e8) + e16);
                    }
                }
            }
            tacc += wt[tile] * ep;
            #pragma unroll
            for (int mi = 0; mi < 4; ++mi)
                #pragma unroll
                for (int ni = 0; ni < 4; ++ni)
                    acc[mi][ni] = f32x4v{0.f, 0.f, 0.f, 0.f};
        }

        if (s < 7) {
            asm volatile("s_waitcnt vmcnt(0)" ::: "memory");  // next buf landed
            __builtin_amdgcn_s_barrier();
        }
    }

    // block reduction -> plain partial store (no fence, no atomic)
    #pragma unroll
    for (int off = 32; off; off >>= 1) tacc += __shfl_down(tacc, off, 64);
    if (ln == 0) redbuf[wv] = tacc;
    __syncthreads();
    if (tid == 0)
        partials[blockIdx.x] =
            (double)(redbuf[0] + redbuf[1] + redbuf[2] + redbuf[3]);
}

// ---------------------------------------------------------------------------
__global__ void final_kernel(const double* __restrict__ partials,
                             float* __restrict__ out) {
    __shared__ double dred[256];
    int tid = threadIdx.x;
    double d = 0.0;
    for (int i = tid; i < NPAIR; i += 256) d += partials[i];
    dred[tid] = d;
    __syncthreads();
    for (int off = 128; off; off >>= 1) {
        if (tid < off) dred[tid] += dred[tid + off];
        __syncthreads();
    }
    if (tid == 0)
        out[0] = (float)(dred[0] / (5.0 * (double)B_HALF * (double)B_HALF));
}

// ---------------------------------------------------------------------------
extern "C" void kernel_launch(void* const* d_in, const int* in_sizes, int n_in,
                              void* d_out, int out_size, void* d_ws, size_t ws_size,
                              hipStream_t stream) {
    const float* src = (const float*)d_in[0];
    const float* tgt = (const float*)d_in[1];
    float* out = (float*)d_out;
    char* ws = (char*)d_ws;

    int*    cntPrep  = (int*)(ws + 0);
    float*  cexp     = (float*)(ws + 16);
    float*  s        = (float*)(ws + 64);      // 256 f32, atomic-accumulated
    double* ssqpart  = (double*)(ws + 2048);   // 256 f64, fully overwritten
    float*  sq       = (float*)(ws + 4096);    // 8192 f32
    double* partials = (double*)(ws + 40960);  // 1040 f64, fully overwritten
    unsigned short* tb = (unsigned short*)(ws + 65536);  // 4 MB bf16

    // zero counters + s[] (ws poisoned 0xAA; not re-poisoned between replays)
    hipMemsetAsync(ws, 0, 2048, stream);

    prep_kernel<<<N_TOTAL / 32, 256, 0, stream>>>(src, tgt, tb, sq, s,
                                                  ssqpart, cntPrep, cexp);
    mmd_kernel<<<NPAIR, 256, 0, stream>>>(tb, sq, cexp, partials);
    final_kernel<<<1, 256, 0, stream>>>(partials, out);
}

// Round 7
// 59.391 us; speedup vs baseline: 2.2518x; 1.0769x over previous
//
#include <hip/hip_runtime.h>
#include <hip/hip_bf16.h>

#define N_TOTAL 8192
#define B_HALF  4096
#define D       256
#define BM      128
#define BK      64
#define NTILES  (N_TOTAL / BM)               // 64
#define NBLK    (NTILES * (NTILES + 1) / 2)  // 2080
#define NPAIR   (NBLK / 2)                   // 1040
#define PREP_BLOCKS (N_TOTAL / 32)           // 256

typedef __bf16 bf16x8v __attribute__((ext_vector_type(8)));
typedef float  f32x4v  __attribute__((ext_vector_type(4)));

__device__ __forceinline__ unsigned short f2bf(float x) {
    unsigned int u = __float_as_uint(x);
    return (unsigned short)((u + 0x7FFFu + ((u >> 16) & 1u)) >> 16);
}
__device__ __forceinline__ float bf2f(unsigned short b) {
    return __uint_as_float(((unsigned int)b) << 16);
}

__device__ __forceinline__ void gload_lds16(const void* g, void* l) {
    __builtin_amdgcn_global_load_lds(
        (const __attribute__((address_space(1))) unsigned int*)g,
        (__attribute__((address_space(3))) unsigned int*)l,
        16, 0, 0);
}

// ---------------------------------------------------------------------------
// prep: f32 -> bf16 (ws), row norms sq[], per-block column-sum partials and
// per-block sum(sq) partials. NO atomics, NO ticket, NO fences, and nothing
// here needs zero-initialized workspace (everything is fully overwritten).
// ---------------------------------------------------------------------------
__global__ void prep_kernel(const float* __restrict__ src,
                            const float* __restrict__ tgt,
                            unsigned short* __restrict__ tb,
                            float* __restrict__ sq,
                            float* __restrict__ colsum_part,  // [256][256]
                            double* __restrict__ sumsq_part)  // [256]
{
    __shared__ float colpart[4][256];
    __shared__ double wsum[4];
    int tid = threadIdx.x;
    int wv = tid >> 6, ln = tid & 63;
    int row0 = blockIdx.x * 32 + wv * 8;

    float cp0 = 0.f, cp1 = 0.f, cp2 = 0.f, cp3 = 0.f;
    double dsum = 0.0;

    for (int t = 0; t < 8; ++t) {
        int row = row0 + t;
        const float* p = (row < B_HALF) ? (src + (size_t)row * D)
                                        : (tgt + (size_t)(row - B_HALF) * D);
        float4 v = *(const float4*)(p + ln * 4);
        unsigned short b0 = f2bf(v.x), b1 = f2bf(v.y), b2 = f2bf(v.z), b3 = f2bf(v.w);
        float x0 = bf2f(b0), x1 = bf2f(b1), x2 = bf2f(b2), x3 = bf2f(b3);
        ushort4 u; u.x = b0; u.y = b1; u.z = b2; u.w = b3;
        *(ushort4*)(tb + (size_t)row * D + ln * 4) = u;

        cp0 += x0; cp1 += x1; cp2 += x2; cp3 += x3;

        float sqp = x0 * x0 + x1 * x1 + x2 * x2 + x3 * x3;
        #pragma unroll
        for (int off = 32; off; off >>= 1) sqp += __shfl_down(sqp, off, 64);
        if (ln == 0) { sq[row] = sqp; dsum += (double)sqp; }
    }
    colpart[wv][ln * 4 + 0] = cp0;
    colpart[wv][ln * 4 + 1] = cp1;
    colpart[wv][ln * 4 + 2] = cp2;
    colpart[wv][ln * 4 + 3] = cp3;
    if (ln == 0) wsum[wv] = dsum;
    __syncthreads();
    colsum_part[blockIdx.x * 256 + tid] =
        colpart[0][tid] + colpart[1][tid] + colpart[2][tid] + colpart[3][tid];
    if (tid == 0)
        sumsq_part[blockIdx.x] = wsum[0] + wsum[1] + wsum[2] + wsum[3];
}

// ---------------------------------------------------------------------------
// bw: closed-form bandwidth from the partials.
//   sum(L2) = 2n*sum(sq) - 2*||colsum||^2 ; cexp = log2(e)/(16*bw)
// ---------------------------------------------------------------------------
__global__ void bw_kernel(const float* __restrict__ colsum_part,
                          const double* __restrict__ sumsq_part,
                          float* __restrict__ cexp) {
    __shared__ double red1[256], red2[256];
    int tid = threadIdx.x;
    float cs = 0.f;
    for (int b = 0; b < PREP_BLOCKS; ++b)
        cs += colsum_part[b * 256 + tid];          // coalesced across threads
    red1[tid] = sumsq_part[tid];                   // 256 prep blocks
    red2[tid] = (double)cs * (double)cs;
    __syncthreads();
    for (int off = 128; off; off >>= 1) {
        if (tid < off) { red1[tid] += red1[tid + off]; red2[tid] += red2[tid + off]; }
        __syncthreads();
    }
    if (tid == 0) {
        double sl2 = 2.0 * (double)N_TOTAL * red1[0] - 2.0 * red2[0];
        double bw = sl2 / ((double)N_TOTAL * N_TOTAL - (double)N_TOTAL);
        cexp[0] = (float)(1.4426950408889634 / (16.0 * bw));
    }
}

// ---------------------------------------------------------------------------
// mmd: each block = TWO consecutive triangle tiles (128x128), 8 fat K-steps,
// T3-minimum schedule: dbuf LDS, stage(s+1) issued FIRST, then ds_read+MFMA
// of step s, then ONE vmcnt(0)+s_barrier per step. Tile0's exp epilogue
// overlaps tile1's first stage. Plain partials store (no fence/atomic).
// ---------------------------------------------------------------------------
__device__ __forceinline__ void stage_tiles(const unsigned short* __restrict__ tb,
                                            int rowBase, int colBase, int kb0,
                                            int wv, int ln,
                                            unsigned short* ldsA,
                                            unsigned short* ldsB) {
    #pragma unroll
    for (int i = 0; i < 4; ++i) {
        int o = i * 4096 + wv * 1024 + ln * 16;          // linear LDS byte off
        int rowl = o >> 7;                               // 128 B per row
        int colb = (o & 127) ^ ((rowl & 7) << 4);        // pre-swizzled source
        gload_lds16(tb + (size_t)(rowBase + rowl) * D + kb0 + (colb >> 1),
                    (char*)ldsA + i * 4096 + wv * 1024);
        gload_lds16(tb + (size_t)(colBase + rowl) * D + kb0 + (colb >> 1),
                    (char*)ldsB + i * 4096 + wv * 1024);
    }
}

__global__ __launch_bounds__(256, 2)
void mmd_kernel(const unsigned short* __restrict__ tb,
                const float* __restrict__ sq,
                const float* __restrict__ cexp_p,
                double* __restrict__ partials) {
    __shared__ __align__(16) unsigned short lds[2][2][BM * BK];  // 64 KB
    __shared__ float sqi[2][BM], sqj[2][BM];
    __shared__ float redbuf[4];

    // decode pair: tiles t0 = 2*bid, t1 = t0+1 of the lower triangle
    int t0 = blockIdx.x * 2;
    int r0 = (int)((sqrtf(8.0f * (float)t0 + 1.0f) - 1.0f) * 0.5f);
    while ((r0 + 1) * (r0 + 2) / 2 <= t0) ++r0;
    while (r0 * (r0 + 1) / 2 > t0) --r0;
    int c0 = t0 - r0 * (r0 + 1) / 2;
    int r1 = r0, c1 = c0 + 1;
    if (c1 > r0) { r1 = r0 + 1; c1 = 0; }

    const int rowB[2] = {r0 * BM, r1 * BM};
    const int colB[2] = {c0 * BM, c1 * BM};
    // per-tile weight: sign (block-uniform; B_HALF multiple of BM) x triangle
    float wt[2];
    wt[0] = (((r0 < NTILES / 2) == (c0 < NTILES / 2)) ? 1.f : -1.f) * (r0 != c0 ? 2.f : 1.f);
    wt[1] = (((r1 < NTILES / 2) == (c1 < NTILES / 2)) ? 1.f : -1.f) * (r1 != c1 ? 2.f : 1.f);

    int tid = threadIdx.x;
    int wv = tid >> 6, ln = tid & 63;
    int wr = wv >> 1, wc = wv & 1;
    int lo = ln & 15, hi = ln >> 4;

    // stage step 0 (tile0, ks=0) immediately; overlap sq loads under it
    stage_tiles(tb, rowB[0], colB[0], 0, wv, ln, lds[0][0], lds[0][1]);

    if (tid < BM) { sqi[0][tid] = sq[rowB[0] + tid]; sqi[1][tid] = sq[rowB[1] + tid]; }
    else { int u = tid - BM; sqj[0][u] = sq[colB[0] + u]; sqj[1][u] = sq[colB[1] + u]; }
    float cexp = cexp_p[0];

    __syncthreads();                 // drains vmcnt(0)+lgkmcnt(0): buf0 ready

    f32x4v acc[4][4] = {};
    float tacc = 0.f;

    #pragma unroll
    for (int s = 0; s < 8; ++s) {    // step = (tile = s>>2, ks = s&3)
        const int cur = s & 1;
        const int tile = s >> 2;

        if (s < 7) {                 // issue next step's stage FIRST
            const int tn = (s + 1) >> 2, kn = (s + 1) & 3;
            stage_tiles(tb, rowB[tn], colB[tn], kn * BK, wv, ln,
                        lds[cur ^ 1][0], lds[cur ^ 1][1]);
            __builtin_amdgcn_sched_barrier(0);   // keep stage issue first
        }

        // read this step's fragments (swizzled, conflict-free)
        bf16x8v a[2][4], b[2][4];
        #pragma unroll
        for (int kk = 0; kk < 2; ++kk) {
            #pragma unroll
            for (int mi = 0; mi < 4; ++mi) {
                int rowl = wr * 64 + mi * 16 + lo;
                int colb = (kk * 64 + hi * 16) ^ ((rowl & 7) << 4);
                a[kk][mi] = *(const bf16x8v*)((const char*)lds[cur][0] + rowl * 128 + colb);
            }
            #pragma unroll
            for (int ni = 0; ni < 4; ++ni) {
                int rowl = wc * 64 + ni * 16 + lo;
                int colb = (kk * 64 + hi * 16) ^ ((rowl & 7) << 4);
                b[kk][ni] = *(const bf16x8v*)((const char*)lds[cur][1] + rowl * 128 + colb);
            }
        }

        __builtin_amdgcn_s_setprio(1);
        #pragma unroll
        for (int kk = 0; kk < 2; ++kk)
            #pragma unroll
            for (int mi = 0; mi < 4; ++mi)
                #pragma unroll
                for (int ni = 0; ni < 4; ++ni)
                    acc[mi][ni] = __builtin_amdgcn_mfma_f32_16x16x32_bf16(
                        a[kk][mi], b[kk][ni], acc[mi][ni], 0, 0, 0);
        __builtin_amdgcn_s_setprio(0);

        if ((s & 3) == 3) {
            // epilogue for `tile` (VALU; overlaps the in-flight stage)
            // C/D layout (16x16x32): col = lane&15, row = (lane>>4)*4 + reg
            float ep = 0.f;
            #pragma unroll
            for (int mi = 0; mi < 4; ++mi) {
                float si4[4];
                #pragma unroll
                for (int rg = 0; rg < 4; ++rg)
                    si4[rg] = sqi[tile][wr * 64 + mi * 16 + hi * 4 + rg];
                #pragma unroll
                for (int ni = 0; ni < 4; ++ni) {
                    float sj = sqj[tile][wc * 64 + ni * 16 + lo];
                    #pragma unroll
                    for (int rg = 0; rg < 4; ++rg) {
                        float arg = (2.0f * acc[mi][ni][rg] - (si4[rg] + sj)) * cexp;
                        float e0 = __builtin_amdgcn_exp2f(arg);
                        float e2 = e0 * e0, e4 = e2 * e2, e8 = e4 * e4, e16 = e8 * e8;
                        ep += (e0 + e2) + ((e4 + e8) + e16);
                    }
                }
            }
            tacc += wt[tile] * ep;
            #pragma unroll
            for (int mi = 0; mi < 4; ++mi)
                #pragma unroll
                for (int ni = 0; ni < 4; ++ni)
                    acc[mi][ni] = f32x4v{0.f, 0.f, 0.f, 0.f};
        }

        if (s < 7) {
            asm volatile("s_waitcnt vmcnt(0)" ::: "memory");  // next buf landed
            __builtin_amdgcn_s_barrier();
        }
    }

    // block reduction -> plain partial store (no fence, no atomic)
    #pragma unroll
    for (int off = 32; off; off >>= 1) tacc += __shfl_down(tacc, off, 64);
    if (ln == 0) redbuf[wv] = tacc;
    __syncthreads();
    if (tid == 0)
        partials[blockIdx.x] =
            (double)(redbuf[0] + redbuf[1] + redbuf[2] + redbuf[3]);
}

// ---------------------------------------------------------------------------
__global__ void final_kernel(const double* __restrict__ partials,
                             float* __restrict__ out) {
    __shared__ double dred[256];
    int tid = threadIdx.x;
    double d = 0.0;
    for (int i = tid; i < NPAIR; i += 256) d += partials[i];
    dred[tid] = d;
    __syncthreads();
    for (int off = 128; off; off >>= 1) {
        if (tid < off) dred[tid] += dred[tid + off];
        __syncthreads();
    }
    if (tid == 0)
        out[0] = (float)(dred[0] / (5.0 * (double)B_HALF * (double)B_HALF));
}

// ---------------------------------------------------------------------------
extern "C" void kernel_launch(void* const* d_in, const int* in_sizes, int n_in,
                              void* d_out, int out_size, void* d_ws, size_t ws_size,
                              hipStream_t stream) {
    const float* src = (const float*)d_in[0];
    const float* tgt = (const float*)d_in[1];
    float* out = (float*)d_out;
    char* ws = (char*)d_ws;

    // all ws buffers are fully overwritten every call -> NO memset node
    float*  cexp     = (float*)(ws + 16);
    double* ssqpart  = (double*)(ws + 2048);    // 256 f64
    float*  sq       = (float*)(ws + 4096);     // 8192 f32 (ends 36864)
    double* partials = (double*)(ws + 36864);   // 1040 f64 (ends 45184)
    float*  cspart   = (float*)(ws + 131072);   // 256*256 f32 (ends 393216)
    unsigned short* tb = (unsigned short*)(ws + 1048576);  // 4 MB bf16

    prep_kernel<<<PREP_BLOCKS, 256, 0, stream>>>(src, tgt, tb, sq, cspart,
                                                 ssqpart);
    bw_kernel<<<1, 256, 0, stream>>>(cspart, ssqpart, cexp);
    mmd_kernel<<<NPAIR, 256, 0, stream>>>(tb, sq, cexp, partials);
    final_kernel<<<1, 256, 0, stream>>>(partials, out);
}